// Round 6
// baseline (202.445 us; speedup 1.0000x reference)
//
#include <hip/hip_runtime.h>
#include <cstdint>
#include <cstddef>

#define Bn 16
#define Cn 64
#define Hn 256
#define Wn 256
#define HWn (Hn * Wn)          // 65536
#define TH 8
#define TW 64
#define ROWS (TH + 2)          // 10
#define COLS (TW + 2)          // 66
#define NBLK (Wn / TW * Hn / TH * Bn)   // 2048

typedef int i32x4 __attribute__((ext_vector_type(4)));

// ---------------- kernel C: pack weight sign bits + per-co params -------------
__global__ __launch_bounds__(64) void pack_weights(const float* __restrict__ w,
                                                   const float* __restrict__ b0g,
                                                   const float* __restrict__ pwg,
                                                   const float* __restrict__ b1g,
                                                   uint64_t* __restrict__ wbits,
                                                   float4* __restrict__ par) {
    const int co = blockIdx.x;
    const int ci = threadIdx.x;
    const float* wp = w + ((size_t)co * Cn + ci) * 9;
    float v[9];
    float asum = 0.f;
    #pragma unroll
    for (int t = 0; t < 9; ++t) { v[t] = wp[t]; asum += fabsf(v[t]); }
    uint64_t m[9];
    #pragma unroll
    for (int t = 0; t < 9; ++t) m[t] = __ballot(v[t] > 0.f);
    #pragma unroll
    for (int off = 32; off; off >>= 1) asum += __shfl_xor(asum, off);
    if (ci == 0) {
        #pragma unroll
        for (int t = 0; t < 9; ++t) wbits[co * 9 + t] = m[t];
        par[co] = make_float4(asum * (1.f / (Cn * 9)), b0g[co], pwg[co], b1g[co]);
    }
}

// ---------------- fused kernel: pack i8 signs to LDS + i8-MFMA conv -----------
__global__ __launch_bounds__(256, 3) void fused(const float* __restrict__ x,
                                                const float* __restrict__ rdk,
                                                const float* __restrict__ rdb,
                                                const uint64_t* __restrict__ wbits,
                                                const float4* __restrict__ par,
                                                float* __restrict__ out) {
    // act tile: [row][col][ci] i8 (+1/-1, 0 in halo). ci-chunks (16B) are
    // XOR-swizzled by (col&3) so MFMA-fragment b128 reads are bank-uniform.
    __shared__ __align__(16) signed char s_act[ROWS * COLS * 64];   // 42240 B
    __shared__ float4 s_par[Cn];
    __shared__ float2 s_rd[Cn];

    const int tid = threadIdx.x;

    // XCD-chunked bijective swizzle (2048 % 8 == 0): y-adjacent tiles share XCD L2
    const int hw_id   = blockIdx.x;
    const int logical = (hw_id & 7) * (NBLK / 8) + (hw_id >> 3);
    const int w0 = (logical & 3) * TW;
    const int h0 = ((logical >> 2) & 31) * TH;
    const int n  = logical >> 7;

    if (tid < Cn) {
        s_par[tid] = par[tid];
        s_rd[tid]  = make_float2(rdk[tid], rdb[tid]);
    }
    __syncthreads();

    // -------- phase 1: sign(x*k+b) -> i8 tile in LDS --------------------------
    const float* xn = x + (size_t)n * Cn * HWn;
    for (int pix = tid; pix < ROWS * COLS; pix += 256) {
        const int r = pix / COLS;
        const int c = pix - r * COLS;
        const int gh = h0 - 1 + r, gw = w0 - 1 + c;
        signed char* dst = s_act + pix * 64;
        if (gh >= 0 && gh < Hn && gw >= 0 && gw < Wn) {
            const float* xp = xn + (size_t)gh * Wn + gw;
            #pragma unroll
            for (int g = 0; g < 4; ++g) {
                unsigned wd[4];
                #pragma unroll
                for (int q = 0; q < 4; ++q) {
                    unsigned v = 0;
                    #pragma unroll
                    for (int b = 0; b < 4; ++b) {
                        const int ci = g * 16 + q * 4 + b;
                        const float2 kb = s_rd[ci];
                        const float a = fmaf(xp[(size_t)ci * HWn], kb.x, kb.y);
                        v |= (unsigned)(unsigned char)(a > 0.f ? 1 : -1) << (8 * b);
                    }
                    wd[q] = v;
                }
                i32x4 t = {(int)wd[0], (int)wd[1], (int)wd[2], (int)wd[3]};
                *(i32x4*)(dst + ((g ^ (c & 3)) * 16)) = t;
            }
        } else {
            const i32x4 z = {0, 0, 0, 0};
            #pragma unroll
            for (int g = 0; g < 4; ++g) *(i32x4*)(dst + g * 16) = z;
        }
    }
    __syncthreads();

    // -------- phase 2: 9-tap i8 MFMA conv + fused epilogue --------------------
    const int lane = tid & 63;
    const int g    = lane >> 4;          // k-chunk group 0..3
    const int ln   = lane & 15;
    const int cobase = (tid >> 6) * 16;  // wave's 16 output channels

    // A-frags (weights, M=co, K=ci per tap) built once from sign bits.
    // lane: m = ln -> co = cobase+ln ; bytes e: ci = g*16+e (same map as B).
    i32x4 afr[9];
    {
        const uint64_t* wbp = wbits + (size_t)(cobase + ln) * 9;
        #pragma unroll
        for (int t = 0; t < 9; ++t) {
            const unsigned slice = (unsigned)(wbp[t] >> (g * 16)) & 0xFFFFu;
            unsigned wq[4];
            #pragma unroll
            for (int q = 0; q < 4; ++q) {
                unsigned v = 0;
                #pragma unroll
                for (int b = 0; b < 4; ++b)
                    v |= (unsigned)(unsigned char)(((slice >> (q * 4 + b)) & 1) ? 1 : -1)
                         << (8 * b);
                wq[q] = v;
            }
            i32x4 t4 = {(int)wq[0], (int)wq[1], (int)wq[2], (int)wq[3]};
            afr[t] = t4;
        }
    }

    // C/D: col = lane&15 = pixel, row = (lane>>4)*4 + j = co offset
    const int co_out0 = cobase + g * 4;
    float4 pj[4];
    #pragma unroll
    for (int j = 0; j < 4; ++j) pj[j] = s_par[co_out0 + j];

    // swizzle offset per dw is lane-constant: (wc multiple of 16)
    int swz[3];
    #pragma unroll
    for (int dw = 0; dw < 3; ++dw) swz[dw] = (g ^ ((dw + ln) & 3)) * 16;

    const size_t obase0 = ((size_t)(n * Cn + co_out0)) * HWn
                        + (size_t)h0 * Wn + w0 + ln;

    #pragma unroll 2
    for (int nt = 0; nt < 32; ++nt) {
        const int r  = nt >> 2;
        const int wc = (nt & 3) * 16;
        i32x4 acc = {0, 0, 0, 0};
        #pragma unroll
        for (int dh = 0; dh < 3; ++dh) {
            const int rowb = (r + dh) * COLS;
            #pragma unroll
            for (int dw = 0; dw < 3; ++dw) {
                const int c = wc + dw + ln;
                const i32x4 bfr = *(const i32x4*)(s_act + (rowb + c) * 64 + swz[dw]);
                acc = __builtin_amdgcn_mfma_i32_16x16x64_i8(afr[dh * 3 + dw], bfr,
                                                            acc, 0, 0, 0);
            }
        }
        const size_t po = obase0 + (size_t)r * Wn + wc;
        #pragma unroll
        for (int j = 0; j < 4; ++j) {
            const float4 p = pj[j];
            float y = fmaf(p.x, (float)acc[j], p.y);
            y = (y >= 0.f) ? y : y * p.z;
            y += p.w;
            const size_t gi = po + (size_t)j * HWn;
            out[gi] = y + x[gi];
        }
    }
}

// ---------------- host launcher ----------------
extern "C" void kernel_launch(void* const* d_in, const int* in_sizes, int n_in,
                              void* d_out, int out_size, void* d_ws, size_t ws_size,
                              hipStream_t stream) {
    const float* x      = (const float*)d_in[0];
    const float* rd_k   = (const float*)d_in[1];
    const float* rd_b   = (const float*)d_in[2];
    // d_in[3] = beta: unused in forward (STE forward = hard sign)
    const float* conv_w = (const float*)d_in[4];
    const float* pb0    = (const float*)d_in[5];
    const float* pw     = (const float*)d_in[6];
    const float* pb1    = (const float*)d_in[7];
    float* out = (float*)d_out;

    uint8_t* ws = (uint8_t*)d_ws;
    uint64_t* wbits = (uint64_t*)ws;                       // 4608 B
    float4*   par   = (float4*)(ws + 4608);                // 1024 B

    pack_weights<<<Cn, 64, 0, stream>>>(conv_w, pb0, pw, pb1, wbits, par);
    fused<<<NBLK, 256, 0, stream>>>(x, rd_k, rd_b, wbits, par, out);
}

// Round 7
// 166.635 us; speedup vs baseline: 1.2149x; 1.2149x over previous
//
#include <hip/hip_runtime.h>
#include <cstdint>
#include <cstddef>

#define Bn 16
#define Cn 64
#define Hn 256
#define Wn 256
#define HWn (Hn * Wn)          // 65536
#define PIX (Bn * HWn)         // 1048576
#define RS 258                 // padded row stride (u64 elements)
#define IS (RS * RS)           // padded image size (u64) = 66564

typedef unsigned long long u64;
typedef u64   u64x2 __attribute__((ext_vector_type(2)));
typedef float f32x4 __attribute__((ext_vector_type(4)));

// ---- kernel C: weight sign bits + per-co params + edge-corr sums + pad zero ---
__global__ __launch_bounds__(64) void pack_weights(const float* __restrict__ w,
                                                   const float* __restrict__ b0g,
                                                   const float* __restrict__ pwg,
                                                   const float* __restrict__ b1g,
                                                   u64* __restrict__ wbits,
                                                   float4* __restrict__ par,
                                                   int* __restrict__ corrx,
                                                   u64* __restrict__ act) {
    const int co = blockIdx.x;
    const int ci = threadIdx.x;
    const float* wp = w + ((size_t)co * Cn + ci) * 9;
    float v[9];
    float asum = 0.f;
    #pragma unroll
    for (int t = 0; t < 9; ++t) { v[t] = wp[t]; asum += fabsf(v[t]); }
    u64 m[9];
    #pragma unroll
    for (int t = 0; t < 9; ++t) m[t] = __ballot(v[t] > 0.f);
    #pragma unroll
    for (int off = 32; off; off >>= 1) asum += __shfl_xor(asum, off);
    if (ci == 0) {
        int c[9];
        #pragma unroll
        for (int t = 0; t < 9; ++t) {
            wbits[co * 9 + t] = m[t];
            c[t] = 64 - 2 * (int)__popcll(m[t]);
        }
        int* cx = corrx + co * 8;
        cx[0] = c[0] + c[1] + c[2];   // top row pad
        cx[1] = c[6] + c[7] + c[8];   // bottom row pad
        cx[2] = c[0] + c[3] + c[6];   // left col pad
        cx[3] = c[2] + c[5] + c[8];   // right col pad
        cx[4] = c[0]; cx[5] = c[2];   // corner overlaps (top-left, top-right)
        cx[6] = c[6]; cx[7] = c[8];   // (bottom-left, bottom-right)
        par[co] = make_float4(asum * (1.f / (Cn * 9)), b0g[co], pwg[co], b1g[co]);
    }
    // zero the pad ring of image `co` (first 16 blocks)
    if (co < Bn) {
        u64* a = act + (size_t)co * IS;
        for (int i = ci; i < 2 * RS + 2 * (RS - 2); i += 64) {
            int r, c;
            if (i < RS)               { r = 0;      c = i; }
            else if (i < 2 * RS)      { r = RS - 1; c = i - RS; }
            else if (i < 2*RS + RS-2) { r = i - 2 * RS + 1;          c = 0; }
            else                      { r = i - (2 * RS + RS - 2) + 1; c = RS - 1; }
            a[(size_t)r * RS + c] = 0;
        }
    }
}

// ---- kernel A: binarize + bit-pack activations into padded bitplane ----------
__global__ __launch_bounds__(256) void pack_act(const float* __restrict__ x,
                                                const float* __restrict__ rdk,
                                                const float* __restrict__ rdb,
                                                u64* __restrict__ act) {
    const int t  = blockIdx.x * 256 + threadIdx.x;   // 0 .. PIX/4-1
    const int p0 = t << 2;
    const int n  = p0 >> 16;
    const int hw = p0 & (HWn - 1);
    const int h  = hw >> 8, w = hw & 255;
    const float* xb = x + (size_t)n * Cn * HWn + hw;
    u64 b0 = 0, b1 = 0, b2 = 0, b3 = 0;
    #pragma unroll 16
    for (int ci = 0; ci < Cn; ++ci) {
        const float k  = rdk[ci];
        const float bb = rdb[ci];
        const f32x4 v = __builtin_nontemporal_load(
            reinterpret_cast<const f32x4*>(xb + (size_t)ci * HWn));
        const u64 bit = 1ull << ci;
        if (fmaf(v.x, k, bb) > 0.f) b0 |= bit;
        if (fmaf(v.y, k, bb) > 0.f) b1 |= bit;
        if (fmaf(v.z, k, bb) > 0.f) b2 |= bit;
        if (fmaf(v.w, k, bb) > 0.f) b3 |= bit;
    }
    u64* o = act + (size_t)n * IS + (size_t)(h + 1) * RS + (w + 1);
    o[0] = b0; o[1] = b1; o[2] = b2; o[3] = b3;
}

// ---- kernel B: barrier-free XNOR-popcount conv + fused epilogue --------------
__global__ __launch_bounds__(256) void bconv(const u64* __restrict__ act,
                                             const u64* __restrict__ wbits,
                                             const float4* __restrict__ par,
                                             const int* __restrict__ corrx,
                                             const float* __restrict__ x,
                                             float* __restrict__ out) {
    const int tid = threadIdx.x;
    // XCD-chunked bijective swizzle (1024 % 8 == 0): h-adjacent blocks share
    // actbit halo rows in the same XCD's L2.
    const int bid     = blockIdx.x;
    const int logical = (bid & 7) * (1024 / 8) + (bid >> 3);
    const int t  = logical * 256 + tid;
    const int p0 = t << 2;                 // 4 consecutive pixels
    const int n  = p0 >> 16;
    const int hw = p0 & (HWn - 1);
    const int h  = hw >> 8, w = hw & 255;  // w % 4 == 0

    // A-window: pixel rows h-1..h+1, pixel cols w-1..w+4 -> padded [h..h+2][w..w+5]
    const u64* ab = act + (size_t)n * IS + (size_t)h * RS + w;
    u64 A[3][6];
    #pragma unroll
    for (int dh = 0; dh < 3; ++dh) {
        const u64x2 q0 = *reinterpret_cast<const u64x2*>(ab + (size_t)dh * RS);
        const u64x2 q1 = *reinterpret_cast<const u64x2*>(ab + (size_t)dh * RS + 2);
        const u64x2 q2 = *reinterpret_cast<const u64x2*>(ab + (size_t)dh * RS + 4);
        A[dh][0] = q0.x; A[dh][1] = q0.y; A[dh][2] = q1.x;
        A[dh][3] = q1.y; A[dh][4] = q2.x; A[dh][5] = q2.y;
    }

    const int htop = (h == 0), hbot = (h == Hn - 1);
    const int wl = (w == 0), wr = (w + 3 == Wn - 1);
    const int need = htop | hbot | wl | wr;

    const float* xp = x   + (size_t)n * Cn * HWn + hw;
    float*       op = out + (size_t)n * Cn * HWn + hw;

    f32x4 xv = __builtin_nontemporal_load(reinterpret_cast<const f32x4*>(xp));
    for (int co = 0; co < Cn; ++co) {
        // prefetch next channel's residual while popcounts run
        const int nco = (co < Cn - 1) ? co + 1 : co;
        const f32x4 xn_ = __builtin_nontemporal_load(
            reinterpret_cast<const f32x4*>(xp + (size_t)nco * HWn));

        const u64* wb = wbits + co * 9;    // uniform address -> SGPR loads
        int a0 = 0, a1 = 0, a2 = 0, a3 = 0;
        #pragma unroll
        for (int dh = 0; dh < 3; ++dh) {
            const u64 w0 = wb[dh * 3], w1 = wb[dh * 3 + 1], w2 = wb[dh * 3 + 2];
            a0 += (int)__popcll(A[dh][0] ^ w0) + (int)__popcll(A[dh][1] ^ w1)
                + (int)__popcll(A[dh][2] ^ w2);
            a1 += (int)__popcll(A[dh][1] ^ w0) + (int)__popcll(A[dh][2] ^ w1)
                + (int)__popcll(A[dh][3] ^ w2);
            a2 += (int)__popcll(A[dh][2] ^ w0) + (int)__popcll(A[dh][3] ^ w1)
                + (int)__popcll(A[dh][4] ^ w2);
            a3 += (int)__popcll(A[dh][3] ^ w0) + (int)__popcll(A[dh][4] ^ w1)
                + (int)__popcll(A[dh][5] ^ w2);
        }
        int i0 = 576 - 2 * a0, i1 = 576 - 2 * a1;
        int i2 = 576 - 2 * a2, i3 = 576 - 2 * a3;

        if (need) {
            const int* cx = corrx + co * 8;
            int sb = 0;
            if (htop) sb += cx[0];
            if (hbot) sb += cx[1];
            int s0 = sb, s3 = sb;
            if (wl) { s0 += cx[2]; if (htop) s0 -= cx[4]; if (hbot) s0 -= cx[6]; }
            if (wr) { s3 += cx[3]; if (htop) s3 -= cx[5]; if (hbot) s3 -= cx[7]; }
            i0 -= s0; i1 -= sb; i2 -= sb; i3 -= s3;
        }

        const float4 p = par[co];          // uniform -> s_load
        f32x4 r;
        {
            float y = fmaf(p.x, (float)i0, p.y);
            y = (y >= 0.f) ? y : y * p.z;
            r.x = y + p.w + xv.x;
        }
        {
            float y = fmaf(p.x, (float)i1, p.y);
            y = (y >= 0.f) ? y : y * p.z;
            r.y = y + p.w + xv.y;
        }
        {
            float y = fmaf(p.x, (float)i2, p.y);
            y = (y >= 0.f) ? y : y * p.z;
            r.z = y + p.w + xv.z;
        }
        {
            float y = fmaf(p.x, (float)i3, p.y);
            y = (y >= 0.f) ? y : y * p.z;
            r.w = y + p.w + xv.w;
        }
        __builtin_nontemporal_store(r, reinterpret_cast<f32x4*>(op + (size_t)co * HWn));
        xv = xn_;
    }
}

// ---------------- host launcher ----------------
extern "C" void kernel_launch(void* const* d_in, const int* in_sizes, int n_in,
                              void* d_out, int out_size, void* d_ws, size_t ws_size,
                              hipStream_t stream) {
    const float* x      = (const float*)d_in[0];
    const float* rd_k   = (const float*)d_in[1];
    const float* rd_b   = (const float*)d_in[2];
    // d_in[3] = beta: unused in forward (STE forward = hard sign)
    const float* conv_w = (const float*)d_in[4];
    const float* pb0    = (const float*)d_in[5];
    const float* pw     = (const float*)d_in[6];
    const float* pb1    = (const float*)d_in[7];
    float* out = (float*)d_out;

    uint8_t* ws = (uint8_t*)d_ws;
    u64* act = (u64*)ws;                                  // 16*66564*8 = 8520192 B
    size_t off = (size_t)Bn * IS * 8;
    u64*    wbits = (u64*)(ws + off);    off += (size_t)Cn * 9 * 8;   // 4608 B
    float4* par   = (float4*)(ws + off); off += (size_t)Cn * 16;      // 1024 B
    int*    corrx = (int*)(ws + off);                                  // 2048 B

    pack_weights<<<Cn, 64, 0, stream>>>(conv_w, pb0, pw, pb1, wbits, par, corrx, act);
    pack_act<<<PIX / 4 / 256, 256, 0, stream>>>(x, rd_k, rd_b, act);
    bconv<<<PIX / 4 / 256, 256, 0, stream>>>(act, wbits, par, corrx, x, out);
}

// Round 8
// 159.864 us; speedup vs baseline: 1.2664x; 1.0424x over previous
//
#include <hip/hip_runtime.h>
#include <cstdint>
#include <cstddef>

#define Bn 16
#define Cn 64
#define Hn 256
#define Wn 256
#define HWn (Hn * Wn)          // 65536
#define TH 8                   // tile rows per block (full image width)
#define ROWS (TH + 2)          // 10
#define COLS (Wn + 2)          // 258
#define NBLK (Bn * (Hn / TH))  // 512

typedef unsigned long long u64;
typedef u64   u64x2 __attribute__((ext_vector_type(2)));
typedef float f32x4 __attribute__((ext_vector_type(4)));

// ---- kernel C: weight sign bits + per-co params + edge-corr sums -------------
__global__ __launch_bounds__(64) void pack_weights(const float* __restrict__ w,
                                                   const float* __restrict__ b0g,
                                                   const float* __restrict__ pwg,
                                                   const float* __restrict__ b1g,
                                                   u64* __restrict__ wbits,
                                                   float4* __restrict__ par,
                                                   int* __restrict__ corrx) {
    const int co = blockIdx.x;
    const int ci = threadIdx.x;
    const float* wp = w + ((size_t)co * Cn + ci) * 9;
    float v[9];
    float asum = 0.f;
    #pragma unroll
    for (int t = 0; t < 9; ++t) { v[t] = wp[t]; asum += fabsf(v[t]); }
    u64 m[9];
    #pragma unroll
    for (int t = 0; t < 9; ++t) m[t] = __ballot(v[t] > 0.f);
    #pragma unroll
    for (int off = 32; off; off >>= 1) asum += __shfl_xor(asum, off);
    if (ci == 0) {
        int c[9];
        #pragma unroll
        for (int t = 0; t < 9; ++t) {
            wbits[co * 9 + t] = m[t];
            c[t] = 64 - 2 * (int)__popcll(m[t]);
        }
        int* cx = corrx + co * 8;
        cx[0] = c[0] + c[1] + c[2];   // top row pad
        cx[1] = c[6] + c[7] + c[8];   // bottom row pad
        cx[2] = c[0] + c[3] + c[6];   // left col pad
        cx[3] = c[2] + c[5] + c[8];   // right col pad
        cx[4] = c[0]; cx[5] = c[2];   // corner overlaps
        cx[6] = c[6]; cx[7] = c[8];
        par[co] = make_float4(asum * (1.f / (Cn * 9)), b0g[co], pwg[co], b1g[co]);
    }
}

// ---- fused kernel: pack 10x258 bit tile in LDS + reg-window conv + epilogue ---
__global__ __launch_bounds__(256, 3) void fused(const float* __restrict__ x,
                                                const float* __restrict__ rdk,
                                                const float* __restrict__ rdb,
                                                const u64* __restrict__ wbits,
                                                const float4* __restrict__ par,
                                                const int* __restrict__ corrx,
                                                float* __restrict__ out,
                                                int clobber) {
    __shared__ __align__(16) u64 s_a[ROWS][COLS];   // 20640 B, zero halo
    __shared__ float2 s_rd[Cn];

    const int tid = threadIdx.x;
    // XCD-chunked bijective swizzle (512 % 8 == 0): each XCD owns 2 full images;
    // vertically adjacent strips share re-packed halo-row x lines in its L2.
    const int bid     = blockIdx.x;
    const int logical = (bid & 7) * (NBLK / 8) + (bid >> 3);
    const int n  = logical >> 5;
    const int h0 = (logical & 31) * TH;

    if (tid < Cn) s_rd[tid] = make_float2(rdk[tid], rdb[tid]);
    if (tid < 2 * ROWS) s_a[tid >> 1][(tid & 1) ? (COLS - 1) : 0] = 0;  // pad cols
    __syncthreads();

    // -------- phase 1: binarize+pack rows h0-1 .. h0+8, full width ------------
    const float* xn = x + (size_t)n * Cn * HWn;
    #pragma unroll
    for (int it = 0; it < 5; ++it) {
        const int task = tid + it * 256;        // 0..1279 = 10 rows x 128 pairs
        const int r  = task >> 7;
        const int c  = (task & 127) * 2;
        const int gh = h0 - 1 + r;
        u64 b0 = 0, b1 = 0;
        if (gh >= 0 && gh < Hn) {
            const float* xp = xn + (size_t)gh * Wn + c;
            #pragma unroll 8
            for (int ci = 0; ci < Cn; ++ci) {
                const float2 kb = s_rd[ci];
                const float2 v = *reinterpret_cast<const float2*>(xp + (size_t)ci * HWn);
                const u64 bit = 1ull << ci;
                if (fmaf(v.x, kb.x, kb.y) > 0.f) b0 |= bit;
                if (fmaf(v.y, kb.x, kb.y) > 0.f) b1 |= bit;
            }
        }
        s_a[r][1 + c] = b0;
        s_a[r][2 + c] = b1;
    }
    __syncthreads();

    // -------- phase 2: A-window -> registers, then barrier-free streaming -----
    const int r  = tid >> 5;            // 0..7  (pixel row h0+r)
    const int c0 = (tid & 31) * 8;      // 0..248 (8 consecutive pixels)

    u64 A[3][10];                       // window rows r..r+2, cols c0..c0+9
    #pragma unroll
    for (int dh = 0; dh < 3; ++dh)
        #pragma unroll
        for (int q = 0; q < 5; ++q) {
            const u64x2 t = *reinterpret_cast<const u64x2*>(&s_a[r + dh][c0 + 2 * q]);
            A[dh][2 * q]     = t.x;
            A[dh][2 * q + 1] = t.y;
        }
    // alias barrier: compiler cannot prove this store never happens, so it may
    // NOT rematerialize A from s_a later -> A stays in VGPRs (R4's failure mode)
    if (clobber) s_a[0][tid] = 0;

    const int htop = (h0 == 0) & (r == 0);
    const int hbot = (h0 + TH == Hn) & (r == TH - 1);
    const int wl = (c0 == 0), wr = (c0 == Wn - 8);
    const int need = htop | hbot | wl | wr;
    const int h = h0 + r;

    const float* xp = x   + (size_t)n * Cn * HWn + (size_t)h * Wn + c0;
    float*       op = out + (size_t)n * Cn * HWn + (size_t)h * Wn + c0;

    f32x4 xa = *reinterpret_cast<const f32x4*>(xp);
    f32x4 xb = *reinterpret_cast<const f32x4*>(xp + 4);
    #pragma unroll 2
    for (int co = 0; co < Cn; ++co) {
        // prefetch next channel's residual while popcounts run
        const int nco = (co < Cn - 1) ? co + 1 : co;
        const f32x4 xa_n = *reinterpret_cast<const f32x4*>(xp + (size_t)nco * HWn);
        const f32x4 xb_n = *reinterpret_cast<const f32x4*>(xp + (size_t)nco * HWn + 4);

        const u64* wb = wbits + co * 9;     // uniform address -> SGPR s_loads
        int isum[8];
        #pragma unroll
        for (int p = 0; p < 8; ++p) {
            int acc = 0;
            #pragma unroll
            for (int dh = 0; dh < 3; ++dh) {
                acc += (int)__popcll(A[dh][p]     ^ wb[dh * 3]);
                acc += (int)__popcll(A[dh][p + 1] ^ wb[dh * 3 + 1]);
                acc += (int)__popcll(A[dh][p + 2] ^ wb[dh * 3 + 2]);
            }
            isum[p] = 576 - 2 * acc;
        }

        if (need) {
            const int* cx = corrx + co * 8;
            const int sb = (htop ? cx[0] : 0) + (hbot ? cx[1] : 0);
            #pragma unroll
            for (int p = 0; p < 8; ++p) isum[p] -= sb;
            if (wl) isum[0] -= cx[2] - (htop ? cx[4] : 0) - (hbot ? cx[6] : 0);
            if (wr) isum[7] -= cx[3] - (htop ? cx[5] : 0) - (hbot ? cx[7] : 0);
        }

        const float4 p4 = par[co];          // uniform -> s_load
        f32x4 o0, o1;
        #pragma unroll
        for (int j = 0; j < 4; ++j) {
            float y = fmaf(p4.x, (float)isum[j], p4.y);
            y = (y >= 0.f) ? y : y * p4.z;
            o0[j] = y + p4.w + xa[j];
        }
        #pragma unroll
        for (int j = 0; j < 4; ++j) {
            float y = fmaf(p4.x, (float)isum[4 + j], p4.y);
            y = (y >= 0.f) ? y : y * p4.z;
            o1[j] = y + p4.w + xb[j];
        }
        __builtin_nontemporal_store(o0, reinterpret_cast<f32x4*>(op + (size_t)co * HWn));
        __builtin_nontemporal_store(o1, reinterpret_cast<f32x4*>(op + (size_t)co * HWn + 4));
        xa = xa_n;
        xb = xb_n;
    }
}

// ---------------- host launcher ----------------
extern "C" void kernel_launch(void* const* d_in, const int* in_sizes, int n_in,
                              void* d_out, int out_size, void* d_ws, size_t ws_size,
                              hipStream_t stream) {
    const float* x      = (const float*)d_in[0];
    const float* rd_k   = (const float*)d_in[1];
    const float* rd_b   = (const float*)d_in[2];
    // d_in[3] = beta: unused in forward (STE forward = hard sign)
    const float* conv_w = (const float*)d_in[4];
    const float* pb0    = (const float*)d_in[5];
    const float* pw     = (const float*)d_in[6];
    const float* pb1    = (const float*)d_in[7];
    float* out = (float*)d_out;

    uint8_t* ws = (uint8_t*)d_ws;
    u64*    wbits = (u64*)ws;                    // 4608 B
    float4* par   = (float4*)(ws + 4608);        // 1024 B
    int*    corrx = (int*)(ws + 4608 + 1024);    // 2048 B

    pack_weights<<<Cn, 64, 0, stream>>>(conv_w, pb0, pw, pb1, wbits, par, corrx);
    fused<<<NBLK, 256, 0, stream>>>(x, rd_k, rd_b, wbits, par, corrx, out, 0);
}